// Round 1
// 310.734 us; speedup vs baseline: 1.0049x; 1.0049x over previous
//
#include <hip/hip_runtime.h>

#define IMG_H 512
#define IMG_W 512
#define NBATCH 32
#define BSTRIDE 68          // floats per 8x8 block in LDS (64 data + 4 pad)
#define PLANE (64*BSTRIDE)  // one channel plane (64 blocks)

static __device__ __forceinline__ float clamp01(float v) {
    return fminf(fmaxf(v, 0.0f), 1.0f);
}

// Forward 1D 8-pt transform: out[l] = sum_k in[k] * F[l][k]
// Uses exact parity of the (truncated) DCT constants: row j of F is
// symmetric (j even) / antisymmetric (j odd) in k.
static __device__ __forceinline__ void fwd8(const float in[8], float out[8]) {
    const float p0 = in[0] + in[7], p1 = in[1] + in[6];
    const float p2 = in[2] + in[5], p3 = in[3] + in[4];
    const float m0 = in[0] - in[7], m1 = in[1] - in[6];
    const float m2 = in[2] - in[5], m3 = in[3] - in[4];
    // even rows 0,2,4,6
    const float a  = p0 + p3, bq = p1 + p2;
    const float cd = p0 - p3, dd = p1 - p2;
    out[0] = 0.3536f * (a + bq);
    out[4] = 0.3536f * (a - bq);
    out[2] = 0.4619f * cd + 0.1913f * dd;
    out[6] = 0.1913f * cd - 0.4619f * dd;
    // odd rows 1,3,5,7 (generic 4x4 on m)
    out[1] = 0.4904f*m0 + 0.4157f*m1 + 0.2778f*m2 + 0.0975f*m3;
    out[3] = 0.4157f*m0 - 0.0975f*m1 - 0.4904f*m2 - 0.2778f*m3;
    out[5] = 0.2778f*m0 - 0.4904f*m1 + 0.0975f*m2 + 0.4157f*m3;
    out[7] = 0.0975f*m0 - 0.2778f*m1 + 0.4157f*m2 - 0.4904f*m3;
}

// Inverse 1D 8-pt transform: out[i] = sum_j in[j] * F[j][i]
// Columns satisfy F[j][7-i] = (-1)^j F[j][i] for the literal constants:
// out[i] = e_i + o_i ; out[7-i] = e_i - o_i.
static __device__ __forceinline__ void inv8(const float in[8], float out[8]) {
    // even part: rows 0,2,4,6 against cols 0..3
    const float s04 = 0.3536f * (in[0] + in[4]);
    const float d04 = 0.3536f * (in[0] - in[4]);
    const float t0  = 0.4619f * in[2] + 0.1913f * in[6];
    const float t1  = 0.1913f * in[2] - 0.4619f * in[6];
    const float e0 = s04 + t0, e3 = s04 - t0;
    const float e1 = d04 + t1, e2 = d04 - t1;
    // odd part: rows 1,3,5,7 against cols 0..3 (generic 4x4)
    const float o0 = 0.4904f*in[1] + 0.4157f*in[3] + 0.2778f*in[5] + 0.0975f*in[7];
    const float o1 = 0.4157f*in[1] - 0.0975f*in[3] - 0.4904f*in[5] - 0.2778f*in[7];
    const float o2 = 0.2778f*in[1] - 0.4904f*in[3] + 0.0975f*in[5] + 0.4157f*in[7];
    const float o3 = 0.0975f*in[1] - 0.2778f*in[3] + 0.4157f*in[5] - 0.4904f*in[7];
    out[0] = e0 + o0;  out[7] = e0 - o0;
    out[1] = e1 + o1;  out[6] = e1 - o1;
    out[2] = e2 + o2;  out[5] = e2 - o2;
    out[3] = e3 + o3;  out[4] = e3 - o3;
}

__global__ __launch_bounds__(192) void jpeg_fused_kernel(
    const float* __restrict__ x,
    const float* __restrict__ qL,
    const float* __restrict__ qC,
    float* __restrict__ out_y,
    float* __restrict__ out_xq)
{
    __shared__ __align__(16) float lds[3*PLANE];   // ycbcr-127, later reused for q
    __shared__ float Qt[2][64];
    __shared__ float rQt[2][64];

    const int t = threadIdx.x;

    if (t < 64)       { float q = qL[t];    Qt[0][t]    = q; rQt[0][t]    = 1.0f/q; }
    else if (t < 128) { float q = qC[t-64]; Qt[1][t-64] = q; rQt[1][t-64] = 1.0f/q; }

    const int b   = blockIdx.y;
    const int th0 = (blockIdx.x >> 3) << 6;   // tile pixel-row origin
    const int tw0 = (blockIdx.x & 7) << 6;    // tile pixel-col origin

    const float* xb = x + (((size_t)b*IMG_H + th0) * IMG_W + tw0) * 3;

    // ---------------- phase 1: load + RGB->YCbCr-127 into LDS (block-major)
    #pragma unroll
    for (int it = 0; it < 6; ++it) {
        int q4 = it*192 + t;                  // quad of 4 pixels; 16 quads/row, 64 rows
        if (q4 < 1024) {
            int h = q4 >> 4, wq = q4 & 15;
            const float* p = xb + h*(IMG_W*3) + wq*12;
            float4 v0 = *(const float4*)(p);
            float4 v1 = *(const float4*)(p+4);
            float4 v2 = *(const float4*)(p+8);
            float px[4][3] = {{v0.x,v0.y,v0.z},{v0.w,v1.x,v1.y},
                              {v1.z,v1.w,v2.x},{v2.y,v2.z,v2.w}};
            float yc[3][4];
            #pragma unroll
            for (int i = 0; i < 4; ++i) {
                float r = px[i][0]*255.0f, g = px[i][1]*255.0f, bl = px[i][2]*255.0f;
                yc[0][i] = 0.299f*r + 0.587f*g + 0.114f*bl - 127.0f;
                yc[1][i] = 1.0f - 0.168736f*r - 0.331264f*g + 0.5f*bl;       // 128-127=1
                yc[2][i] = 1.0f + 0.5f*r - 0.418688f*g - 0.081312f*bl;
            }
            int bh = h >> 3, r8 = h & 7, bw = wq >> 1, qi = wq & 1;
            int base = (bh*8 + bw)*BSTRIDE + r8*8 + qi*4;
            #pragma unroll
            for (int c = 0; c < 3; ++c)
                *(float4*)&lds[c*PLANE + base] =
                    make_float4(yc[c][0], yc[c][1], yc[c][2], yc[c][3]);
        }
    }
    __syncthreads();

    // ---------------- phase 2: per block-channel DCT -> quantize -> IDCT
    {
        const int c   = t >> 6;     // 0..2
        const int blk = t & 63;
        float* Lb = &lds[(c*64 + blk)*BSTRIDE];

        float X[8][8];
        #pragma unroll
        for (int i = 0; i < 8; ++i) {
            float4 a  = *(const float4*)(Lb + i*8);
            float4 bb = *(const float4*)(Lb + i*8 + 4);
            X[i][0]=a.x;  X[i][1]=a.y;  X[i][2]=a.z;  X[i][3]=a.w;
            X[i][4]=bb.x; X[i][5]=bb.y; X[i][6]=bb.z; X[i][7]=bb.w;
        }
        // tmp = b @ F^T : forward 1D on each row (contract over F's col index)
        #pragma unroll
        for (int i = 0; i < 8; ++i) {
            float tin[8], tout[8];
            #pragma unroll
            for (int k = 0; k < 8; ++k) tin[k] = X[i][k];
            fwd8(tin, tout);
            #pragma unroll
            for (int l = 0; l < 8; ++l) X[i][l] = tout[l];
        }
        // X = F @ tmp : forward 1D on each column
        #pragma unroll
        for (int l = 0; l < 8; ++l) {
            float tin[8], tout[8];
            #pragma unroll
            for (int j = 0; j < 8; ++j) tin[j] = X[j][l];
            fwd8(tin, tout);
            #pragma unroll
            for (int i = 0; i < 8; ++i) X[i][l] = tout[i];
        }
        // quantize: Xq = round_sin(X/Q) * Q.
        // sin(2*pi*k*v) == sin(2*pi*k*fract(v)) exactly (k integer), so one
        // fract + sin + cos and a Chebyshev recurrence replace 5 sins.
        const int qc = (c > 0) ? 1 : 0;
        #pragma unroll
        for (int i = 0; i < 8; ++i) {
            #pragma unroll
            for (int l = 0; l < 8; ++l) {
                float Q  = Qt[qc][i*8+l];
                float v  = X[i][l] * rQt[qc][i*8+l];
                float f  = __builtin_amdgcn_fractf(v);
                float s1 = __builtin_amdgcn_sinf(f);   // sin(2*pi*v)
                float c1 = __builtin_amdgcn_cosf(f);   // cos(2*pi*v)
                float c2 = c1 + c1;
                float s2 = c2*s1;
                float s3 = c2*s2 - s1;
                float s4 = c2*s3 - s2;
                float s5 = c2*s4 - s3;
                float r  = v - 0.3183098862f*s1 + 0.1591549431f*s2
                             - 0.1061032954f*s3 + 0.0795774715f*s4
                             - 0.0636619772f*s5;
                X[i][l] = r * Q;
            }
        }
        // write Xq: block index = bh_g*64 + bw_g, row-major 8x8 inside
        {
            int bh = blk >> 3, bw = blk & 7;
            size_t xqbase = (((size_t)b*3 + c)*4096
                           + (size_t)((th0>>3) + bh)*64 + ((tw0>>3) + bw)) * 64;
            #pragma unroll
            for (int i = 0; i < 8; ++i) {
                *(float4*)(out_xq + xqbase + i*8)     = make_float4(X[i][0],X[i][1],X[i][2],X[i][3]);
                *(float4*)(out_xq + xqbase + i*8 + 4) = make_float4(X[i][4],X[i][5],X[i][6],X[i][7]);
            }
        }
        // w = F^T @ Xq : inverse 1D on each column (contract over F's row index)
        #pragma unroll
        for (int l = 0; l < 8; ++l) {
            float tin[8], tout[8];
            #pragma unroll
            for (int j = 0; j < 8; ++j) tin[j] = X[j][l];
            inv8(tin, tout);
            #pragma unroll
            for (int i = 0; i < 8; ++i) X[i][l] = tout[i];
        }
        // ib = w @ F : inverse 1D on each row
        #pragma unroll
        for (int i = 0; i < 8; ++i) {
            float tin[8], tout[8];
            #pragma unroll
            for (int k = 0; k < 8; ++k) tin[k] = X[i][k];
            inv8(tin, tout);
            #pragma unroll
            for (int l = 0; l < 8; ++l) X[i][l] = tout[l];
        }
        // q back to LDS (owner-exclusive region; overwrite in place)
        #pragma unroll
        for (int i = 0; i < 8; ++i) {
            *(float4*)(Lb + i*8)     = make_float4(X[i][0],X[i][1],X[i][2],X[i][3]);
            *(float4*)(Lb + i*8 + 4) = make_float4(X[i][4],X[i][5],X[i][6],X[i][7]);
        }
    }
    __syncthreads();

    // ---------------- phase 3: YCbCr->RGB, clip, coalesced store
    float* yb = out_y + (((size_t)b*IMG_H + th0) * IMG_W + tw0) * 3;
    #pragma unroll
    for (int it = 0; it < 6; ++it) {
        int q4 = it*192 + t;
        if (q4 < 1024) {
            int h = q4 >> 4, wq = q4 & 15;
            int bh = h >> 3, r8 = h & 7, bw = wq >> 1, qi = wq & 1;
            int base = (bh*8 + bw)*BSTRIDE + r8*8 + qi*4;
            float4 vy = *(const float4*)&lds[0*PLANE + base];
            float4 vb = *(const float4*)&lds[1*PLANE + base];
            float4 vr = *(const float4*)&lds[2*PLANE + base];
            float Yv[4]={vy.x,vy.y,vy.z,vy.w};
            float Cb[4]={vb.x,vb.y,vb.z,vb.w};
            float Cr[4]={vr.x,vr.y,vr.z,vr.w};
            float o[4][3];
            #pragma unroll
            for (int i = 0; i < 4; ++i) {
                float yv = Yv[i] + 127.0f, cb = Cb[i] + 127.0f, cr = Cr[i] + 127.0f;
                o[i][0] = clamp01((-179.456f    + yv + 1.402f*cr) * (1.0f/255.0f));
                o[i][1] = clamp01(( 135.458816f + yv - 0.344136f*cb - 0.714136f*cr) * (1.0f/255.0f));
                o[i][2] = clamp01((-226.816f    + yv + 1.772f*cb) * (1.0f/255.0f));
            }
            float* p = yb + h*(IMG_W*3) + wq*12;
            *(float4*)(p)   = make_float4(o[0][0],o[0][1],o[0][2],o[1][0]);
            *(float4*)(p+4) = make_float4(o[1][1],o[1][2],o[2][0],o[2][1]);
            *(float4*)(p+8) = make_float4(o[2][2],o[3][0],o[3][1],o[3][2]);
        }
    }
}

extern "C" void kernel_launch(void* const* d_in, const int* in_sizes, int n_in,
                              void* d_out, int out_size, void* d_ws, size_t ws_size,
                              hipStream_t stream) {
    const float* x  = (const float*)d_in[0];
    const float* qL = (const float*)d_in[1];
    const float* qC = (const float*)d_in[2];
    float* out_y  = (float*)d_out;                                    // 32*512*512*3
    float* out_xq = (float*)d_out + (size_t)NBATCH*IMG_H*IMG_W*3;     // then Xq blocks

    dim3 grid(64, NBATCH);   // 8x8 tiles of 64x64 px per image, 32 images
    dim3 block(192);
    jpeg_fused_kernel<<<grid, block, 0, stream>>>(x, qL, qC, out_y, out_xq);
}